// Round 3
// baseline (196.509 us; speedup 1.0000x reference)
//
#include <hip/hip_runtime.h>
#include <math.h>

#define DD 4096
#define EE 64
#define BK 32
#define NEG_SENTINEL -1.0e30f

// global -> LDS direct copy, 16B per lane. LDS dest is wave-uniform base
// (HW adds lane*16); per-lane global src carries the swizzle (m173 pattern).
__device__ __forceinline__ void gload16(const void* g, void* l) {
  __builtin_amdgcn_global_load_lds(
      (const __attribute__((address_space(1))) uint32_t*)(uintptr_t)g,
      (__attribute__((address_space(3))) uint32_t*)(uint32_t)(uintptr_t)l, 16,
      0, 0);
}

// ---------------------------------------------------------------------------
// Kernel 1: partial GEMM  logits[n][e] = sum_k hidden[n][k] * gate_w[e][k]
// Tile: 64 rows x 64 experts x BK=32 k. 256 threads (4 waves), thread 4x4.
// LDS per block: 2 bufs x (A 8KB + B 8KB) = 32KB -> 4 blocks/CU, grid=1024
// blocks -> fully resident (4 waves/SIMD).
// LDS physical layout (A and B identical), row = 128B = 8 float4 chunks:
//   byte(r, c) = r*128 + ((c ^ ((r>>2)&7)) << 4)
// achieved by global_load_lds with pre-swizzled per-lane source columns.
// Read: addr = tx*512 + i*128 + ((kk ^ (tx&7))<<4) -> 2-way max (free).
// 2-phase pipeline: STAGE(next buf) -> compute(cur) -> __syncthreads().
// ---------------------------------------------------------------------------
template <int KSPLIT>
__global__ __launch_bounds__(256, 4) void gemm_partial(
    const float* __restrict__ hidden, const float* __restrict__ gate_w,
    float* __restrict__ part, int nrows) {
  __shared__ __align__(16) char smem[32768];

  const int tid = threadIdx.x;
  const int lane = tid & 63;
  const int wv = tid >> 6;  // wave 0..3
  const int tx = tid & 15;
  const int ty = tid >> 4;  // 0..15
  const int m0 = blockIdx.x * 64;
  const int kslice = DD / KSPLIT;
  const int nt = kslice / BK;  // 32 tiles
  const int k0 = blockIdx.y * kslice;

  // Staging: wave wv stages A/B rows 16wv..16wv+15 (2 x 1KB instrs each).
  // Instr i covers rows 16wv+8i..+7: lane l -> row rowbase+(l>>3),
  // source chunk (l&7) ^ ((r>>2)&7)  (lands in phys slot l&7).
  const char* pA[2];
  const char* pB[2];
#pragma unroll
  for (int i = 0; i < 2; i++) {
    const int r = 16 * wv + 8 * i + (lane >> 3);
    const int col = (((lane & 7) ^ ((r >> 2) & 7)) << 4);
    pA[i] = (const char*)hidden + ((size_t)(m0 + r) * DD + k0) * 4 + col;
    pB[i] = (const char*)gate_w + ((size_t)r * DD + k0) * 4 + col;
  }

  auto stage = [&](int bufsel) {
    char* bA = smem + bufsel * 16384 + wv * 2048;
    char* bB = bA + 8192;
#pragma unroll
    for (int i = 0; i < 2; i++) {
      gload16(pA[i], bA + i * 1024);
      gload16(pB[i], bB + i * 1024);
      pA[i] += BK * 4;
      pB[i] += BK * 4;
    }
  };

  float acc[4][4] = {};
  const int sA = tx & 7;
  const int sB = ty & 7;

  int buf = 0;
  stage(0);
  __syncthreads();  // drains vmcnt(0): buf0 ready

  for (int t = 0; t < nt; t++) {
    if (t + 1 < nt) stage(buf ^ 1);  // issue next tile's loads first
    const char* aBase = smem + buf * 16384 + (tx << 9);
    const char* bBase = smem + buf * 16384 + 8192 + (ty << 9);
#pragma unroll
    for (int kk = 0; kk < 8; kk++) {
      const int oa = (kk ^ sA) << 4;
      const int ob = (kk ^ sB) << 4;
      float4 av[4], bv[4];
#pragma unroll
      for (int i = 0; i < 4; i++)
        av[i] = *(const float4*)(aBase + oa + i * 128);
#pragma unroll
      for (int j = 0; j < 4; j++)
        bv[j] = *(const float4*)(bBase + ob + j * 128);
#pragma unroll
      for (int i = 0; i < 4; i++)
#pragma unroll
        for (int j = 0; j < 4; j++) {
          acc[i][j] = fmaf(av[i].x, bv[j].x, acc[i][j]);
          acc[i][j] = fmaf(av[i].y, bv[j].y, acc[i][j]);
          acc[i][j] = fmaf(av[i].z, bv[j].z, acc[i][j]);
          acc[i][j] = fmaf(av[i].w, bv[j].w, acc[i][j]);
        }
    }
    __syncthreads();  // drains this iter's stage + all LDS reads
    buf ^= 1;
  }

  // Write partial logits: part[ks][row][e]
  float* dst = part + (size_t)blockIdx.y * nrows * EE;
#pragma unroll
  for (int i = 0; i < 4; i++) {
    float4 v = make_float4(acc[i][0], acc[i][1], acc[i][2], acc[i][3]);
    *(float4*)&dst[(size_t)(m0 + 4 * tx + i) * EE + 4 * ty] = v;
  }
}

// ---------------------------------------------------------------------------
// Kernel 2: reduce K-split partials, sqrt(softplus), top-8 (lower-index
// tie-break like lax.top_k), renormalize, scatter probs + routing map.
// One wave (64 lanes) per row; lane == expert.
// ---------------------------------------------------------------------------
__global__ __launch_bounds__(256) void topk_kernel(
    const float* __restrict__ part, const float* __restrict__ bias,
    float* __restrict__ out, int nrows, int ksplit) {
  const int lane = threadIdx.x & 63;
  const int row = blockIdx.x * 4 + (threadIdx.x >> 6);

  float logit = 0.0f;
  for (int s = 0; s < ksplit; s++)
    logit += part[(size_t)s * nrows * EE + (size_t)row * EE + lane];

  // softplus, numerically stable
  float sp = (logit > 0.0f) ? (logit + log1pf(expf(-logit)))
                            : log1pf(expf(logit));
  float score = sqrtf(sp);
  float sel = score + bias[lane];

  float denom = 0.0f;
  bool chosen = false;
#pragma unroll
  for (int t = 0; t < 8; t++) {
    float v = sel;
    int idx = lane;
#pragma unroll
    for (int m = 1; m < 64; m <<= 1) {
      float ov = __shfl_xor(v, m, 64);
      int oi = __shfl_xor(idx, m, 64);
      if (ov > v || (ov == v && oi < idx)) {
        v = ov;
        idx = oi;
      }
    }
    float wscore = __shfl(score, idx, 64);
    denom += wscore;
    if (lane == idx) {
      chosen = true;
      sel = NEG_SENTINEL;
    }
  }
  denom = fmaxf(denom, 1e-12f);

  out[(size_t)row * EE + lane] = chosen ? (score / denom) : 0.0f;
  out[(size_t)nrows * EE + (size_t)row * EE + lane] = chosen ? 1.0f : 0.0f;
}

// ---------------------------------------------------------------------------
extern "C" void kernel_launch(void* const* d_in, const int* in_sizes, int n_in,
                              void* d_out, int out_size, void* d_ws,
                              size_t ws_size, hipStream_t stream) {
  const float* hidden = (const float*)d_in[0];
  const float* gate_w = (const float*)d_in[1];
  const float* bias = (const float*)d_in[2];
  float* out = (float*)d_out;
  float* part = (float*)d_ws;

  const int nrows = in_sizes[0] / DD;  // 16384

  const size_t per = (size_t)nrows * EE * sizeof(float);  // 4 MiB
  int ksplit = (ws_size >= 4 * per) ? 4 : ((ws_size >= 2 * per) ? 2 : 1);

  dim3 block(256);
  dim3 grid(nrows / 64, ksplit);
  if (ksplit == 4)
    gemm_partial<4><<<grid, block, 0, stream>>>(hidden, gate_w, part, nrows);
  else if (ksplit == 2)
    gemm_partial<2><<<grid, block, 0, stream>>>(hidden, gate_w, part, nrows);
  else
    gemm_partial<1><<<grid, block, 0, stream>>>(hidden, gate_w, part, nrows);

  topk_kernel<<<dim3(nrows / 4), dim3(256), 0, stream>>>(part, bias, out,
                                                         nrows, ksplit);
}

// Round 4
// 157.744 us; speedup vs baseline: 1.2458x; 1.2458x over previous
//
#include <hip/hip_runtime.h>
#include <math.h>

#define DD 4096
#define EE 64
#define BK 32
#define TAU 1e-4f
#define NEG_SENTINEL -1.0e30f
#define MAXFIX 16000

typedef __attribute__((ext_vector_type(8))) short short8v;
typedef __attribute__((ext_vector_type(4))) float f32x4;

__device__ __forceinline__ unsigned short f2bf(float x) {
  union { float f; unsigned u; } v;
  v.f = x;
  unsigned r = v.u + 0x7fffu + ((v.u >> 16) & 1u);  // RNE to bf16
  return (unsigned short)(r >> 16);
}
__device__ __forceinline__ float bf2f(unsigned short h) {
  union { float f; unsigned u; } v;
  v.u = ((unsigned)h) << 16;
  return v.f;
}
// swizzled byte offset within a [rows][64B] LDS plane (4x 16B slots per row)
__device__ __forceinline__ int swz(int row, int slot) {
  return row * 64 + ((slot ^ ((row >> 2) & 3)) << 4);
}

// ---------------------------------------------------------------------------
// Kernel 1: bf16-split MFMA partial GEMM. logits = hidden * gate_w^T
// x = x_hi + x_lo (bf16 RNE each); D += Ah*Bh + Ah*Bl + Al*Bh  (f32 accum).
// Block: 128 rows x 64 experts, 4 waves (wave = 32 rows x 64 e = 2x4 tiles
// of 16x16x32). BK=32. LDS: 2 bufs x {A_hi 8K, A_lo 8K, B_hi 4K, B_lo 4K}.
// Frag layout (gfx950): A lane l -> row l&15, k=8*(l>>4)+j ; B symmetric on
// row-major [r][k] tiles; C/D row=(l>>4)*4+reg, col=l&15 (m89-verified).
// ---------------------------------------------------------------------------
template <int KSPLIT>
__global__ __launch_bounds__(256, 2) void gemm_mfma(
    const float* __restrict__ hidden, const float* __restrict__ gate_w,
    float* __restrict__ part, int nrows) {
  __shared__ __align__(16) char smem[49152];  // 2 x 24576

  const int tid = threadIdx.x;
  const int lane = tid & 63;
  const int wv = tid >> 6;
  const int m0 = blockIdx.x * 128;
  const int kslice = DD / KSPLIT;
  const int nsteps = kslice / BK;
  const int k0 = blockIdx.y * kslice;

  // staging ownership
  const int ra = tid & 127;  // A row
  const int ga = tid >> 7;   // A k-half (16 floats)
  const int rb = tid & 63;   // B row (expert)
  const int ub = tid >> 6;   // B slot (8 floats)

  const float* pa = hidden + (size_t)(m0 + ra) * DD + k0 + ga * 16;
  const float* pb = gate_w + (size_t)rb * DD + k0 + ub * 8;

  float4 fa[4], fb[2];
#pragma unroll
  for (int i = 0; i < 4; i++) fa[i] = *(const float4*)(pa + 4 * i);
#pragma unroll
  for (int i = 0; i < 2; i++) fb[i] = *(const float4*)(pb + 4 * i);
  pa += BK;
  pb += BK;

  f32x4 zero4 = {0.f, 0.f, 0.f, 0.f};
  f32x4 acc[2][4];
#pragma unroll
  for (int mt = 0; mt < 2; mt++)
#pragma unroll
    for (int nt = 0; nt < 4; nt++) acc[mt][nt] = zero4;

  const int wm = wv * 32;
  const int fr = lane & 15;
  const int fg = lane >> 4;

  int buf = 0;
  for (int t = 0; t < nsteps; t++) {
    char* base = smem + buf * 24576;
    // ---- convert + LDS write (A: 16 floats -> 2 slots/plane) ----
    float f[16];
#pragma unroll
    for (int i = 0; i < 4; i++) {
      f[4 * i] = fa[i].x; f[4 * i + 1] = fa[i].y;
      f[4 * i + 2] = fa[i].z; f[4 * i + 3] = fa[i].w;
    }
#pragma unroll
    for (int s = 0; s < 2; s++) {
      unsigned wh[4], wl[4];
#pragma unroll
      for (int j = 0; j < 4; j++) {
        float x0 = f[8 * s + 2 * j], x1 = f[8 * s + 2 * j + 1];
        unsigned short h0 = f2bf(x0), h1 = f2bf(x1);
        unsigned short l0 = f2bf(x0 - bf2f(h0)), l1 = f2bf(x1 - bf2f(h1));
        wh[j] = (unsigned)h0 | ((unsigned)h1 << 16);
        wl[j] = (unsigned)l0 | ((unsigned)l1 << 16);
      }
      const int off = swz(ra, 2 * ga + s);
      *(uint4*)(base + off) = make_uint4(wh[0], wh[1], wh[2], wh[3]);
      *(uint4*)(base + 8192 + off) = make_uint4(wl[0], wl[1], wl[2], wl[3]);
    }
    {  // B: 8 floats -> 1 slot/plane
      float g[8] = {fb[0].x, fb[0].y, fb[0].z, fb[0].w,
                    fb[1].x, fb[1].y, fb[1].z, fb[1].w};
      unsigned wh[4], wl[4];
#pragma unroll
      for (int j = 0; j < 4; j++) {
        float x0 = g[2 * j], x1 = g[2 * j + 1];
        unsigned short h0 = f2bf(x0), h1 = f2bf(x1);
        unsigned short l0 = f2bf(x0 - bf2f(h0)), l1 = f2bf(x1 - bf2f(h1));
        wh[j] = (unsigned)h0 | ((unsigned)h1 << 16);
        wl[j] = (unsigned)l0 | ((unsigned)l1 << 16);
      }
      const int off = swz(rb, ub);
      *(uint4*)(base + 16384 + off) = make_uint4(wh[0], wh[1], wh[2], wh[3]);
      *(uint4*)(base + 20480 + off) = make_uint4(wl[0], wl[1], wl[2], wl[3]);
    }
    // ---- issue next tile's global loads (fly during barrier+MFMA) ----
    if (t + 1 < nsteps) {
#pragma unroll
      for (int i = 0; i < 4; i++) fa[i] = *(const float4*)(pa + 4 * i);
#pragma unroll
      for (int i = 0; i < 2; i++) fb[i] = *(const float4*)(pb + 4 * i);
      pa += BK;
      pb += BK;
    }
    __syncthreads();
    // ---- fragments + 24 MFMAs ----
    short8v ah[2], al[2], bh[4], bl[4];
#pragma unroll
    for (int mt = 0; mt < 2; mt++) {
      const int off = swz(wm + mt * 16 + fr, fg);
      ah[mt] = *(const short8v*)(base + off);
      al[mt] = *(const short8v*)(base + 8192 + off);
    }
#pragma unroll
    for (int nt = 0; nt < 4; nt++) {
      const int off = swz(nt * 16 + fr, fg);
      bh[nt] = *(const short8v*)(base + 16384 + off);
      bl[nt] = *(const short8v*)(base + 20480 + off);
    }
#pragma unroll
    for (int mt = 0; mt < 2; mt++)
#pragma unroll
      for (int nt = 0; nt < 4; nt++) {
        acc[mt][nt] = __builtin_amdgcn_mfma_f32_16x16x32_bf16(
            ah[mt], bh[nt], acc[mt][nt], 0, 0, 0);
        acc[mt][nt] = __builtin_amdgcn_mfma_f32_16x16x32_bf16(
            ah[mt], bl[nt], acc[mt][nt], 0, 0, 0);
        acc[mt][nt] = __builtin_amdgcn_mfma_f32_16x16x32_bf16(
            al[mt], bh[nt], acc[mt][nt], 0, 0, 0);
      }
    buf ^= 1;
  }

  // partial logits: part[ks][row][e]
  float* dst = part + (size_t)blockIdx.y * nrows * EE;
#pragma unroll
  for (int mt = 0; mt < 2; mt++)
#pragma unroll
    for (int j = 0; j < 4; j++) {
      const int r = m0 + wm + mt * 16 + fg * 4 + j;
#pragma unroll
      for (int nt = 0; nt < 4; nt++)
        dst[(size_t)r * EE + nt * 16 + fr] = acc[mt][nt][j];
    }
}

// ---------------------------------------------------------------------------
// Kernel 2: reduce partials, sqrt(softplus), top-8 (lax.top_k tie-break),
// renormalize, scatter. Flags rows with selection margin < TAU for exact
// f32 recompute (bf16-split logit error <= ~2e-5, TAU gives 15x headroom).
// ---------------------------------------------------------------------------
__global__ __launch_bounds__(256) void topk_kernel(
    const float* __restrict__ part, const float* __restrict__ bias,
    float* __restrict__ out, int nrows, int ksplit, int* __restrict__ counter,
    int* __restrict__ list) {
  const int lane = threadIdx.x & 63;
  const int row = blockIdx.x * 4 + (threadIdx.x >> 6);

  float logit = 0.0f;
  for (int s = 0; s < ksplit; s++)
    logit += part[(size_t)s * nrows * EE + (size_t)row * EE + lane];

  float sp = (logit > 0.0f) ? (logit + log1pf(expf(-logit)))
                            : log1pf(expf(logit));
  float score = sqrtf(sp);
  float sel = score + bias[lane];

  float denom = 0.0f, v8 = 0.0f;
  bool chosen = false;
#pragma unroll
  for (int t = 0; t < 8; t++) {
    float v = sel;
    int idx = lane;
#pragma unroll
    for (int m = 1; m < 64; m <<= 1) {
      float ov = __shfl_xor(v, m, 64);
      int oi = __shfl_xor(idx, m, 64);
      if (ov > v || (ov == v && oi < idx)) { v = ov; idx = oi; }
    }
    float wscore = __shfl(score, idx, 64);
    denom += wscore;
    v8 = v;
    if (lane == idx) { chosen = true; sel = NEG_SENTINEL; }
  }
  // 9th-best for selection margin
  float v9 = sel;
#pragma unroll
  for (int m = 1; m < 64; m <<= 1) v9 = fmaxf(v9, __shfl_xor(v9, m, 64));
  if (lane == 0 && (v8 - v9) < TAU) {
    int ix = atomicAdd(counter, 1);
    if (ix < MAXFIX) list[ix] = row;
  }

  denom = fmaxf(denom, 1e-12f);
  out[(size_t)row * EE + lane] = chosen ? (score / denom) : 0.0f;
  out[(size_t)nrows * EE + (size_t)row * EE + lane] = chosen ? 1.0f : 0.0f;
}

// ---------------------------------------------------------------------------
// Kernel 3: exact-f32 recompute of flagged rows (few). 256 thr/block:
// expert = tid&63, K-quarter = tid>>6; LDS reduce; wave 0 redoes top-8.
// ---------------------------------------------------------------------------
__global__ __launch_bounds__(256) void fixup_kernel(
    const float* __restrict__ hidden, const float* __restrict__ gate_w,
    const float* __restrict__ bias, const int* __restrict__ counter,
    const int* __restrict__ list, float* __restrict__ out, int nrows) {
  __shared__ float red[EE][4];
  int cnt = *counter;
  if (cnt > MAXFIX) cnt = MAXFIX;
  for (int i = blockIdx.x; i < cnt; i += gridDim.x) {
    const int row = list[i];
    const int e = threadIdx.x & 63;
    const int q = threadIdx.x >> 6;
    const float* hp = hidden + (size_t)row * DD + q * 1024;
    const float* wp = gate_w + (size_t)e * DD + q * 1024;
    float s = 0.f;
    for (int k = 0; k < 1024; k += 4) {
      float4 a = *(const float4*)(hp + k);
      float4 b = *(const float4*)(wp + k);
      s = fmaf(a.w, b.w, fmaf(a.z, b.z, fmaf(a.y, b.y, fmaf(a.x, b.x, s))));
    }
    red[e][q] = s;
    __syncthreads();
    if (threadIdx.x < 64) {
      const int lane = threadIdx.x;
      float logit = red[lane][0] + red[lane][1] + red[lane][2] + red[lane][3];
      float sp = (logit > 0.0f) ? (logit + log1pf(expf(-logit)))
                                : log1pf(expf(logit));
      float score = sqrtf(sp);
      float sel = score + bias[lane];
      float denom = 0.0f;
      bool chosen = false;
#pragma unroll
      for (int t = 0; t < 8; t++) {
        float v = sel;
        int idx = lane;
#pragma unroll
        for (int m = 1; m < 64; m <<= 1) {
          float ov = __shfl_xor(v, m, 64);
          int oi = __shfl_xor(idx, m, 64);
          if (ov > v || (ov == v && oi < idx)) { v = ov; idx = oi; }
        }
        float wscore = __shfl(score, idx, 64);
        denom += wscore;
        if (lane == idx) { chosen = true; sel = NEG_SENTINEL; }
      }
      denom = fmaxf(denom, 1e-12f);
      out[(size_t)row * EE + lane] = chosen ? (score / denom) : 0.0f;
      out[(size_t)nrows * EE + (size_t)row * EE + lane] = chosen ? 1.0f : 0.0f;
    }
    __syncthreads();
  }
}

// ---------------------------------------------------------------------------
extern "C" void kernel_launch(void* const* d_in, const int* in_sizes, int n_in,
                              void* d_out, int out_size, void* d_ws,
                              size_t ws_size, hipStream_t stream) {
  const float* hidden = (const float*)d_in[0];
  const float* gate_w = (const float*)d_in[1];
  const float* bias = (const float*)d_in[2];
  float* out = (float*)d_out;
  char* ws = (char*)d_ws;

  const int nrows = in_sizes[0] / DD;  // 16384

  size_t tail = (ws_size - 65536) & ~(size_t)255;
  int* counter = (int*)(ws + tail);
  int* list = counter + 1;
  float* part = (float*)ws;
  const size_t per = (size_t)nrows * EE * sizeof(float);  // 4 MiB
  const int ksplit = (tail >= 4 * per) ? 4 : 2;

  hipMemsetAsync(counter, 0, sizeof(int), stream);

  dim3 block(256);
  if (ksplit == 4)
    gemm_mfma<4><<<dim3(nrows / 128, 4), block, 0, stream>>>(hidden, gate_w,
                                                             part, nrows);
  else
    gemm_mfma<2><<<dim3(nrows / 128, 2), block, 0, stream>>>(hidden, gate_w,
                                                             part, nrows);
  topk_kernel<<<dim3(nrows / 4), block, 0, stream>>>(part, bias, out, nrows,
                                                     ksplit, counter, list);
  fixup_kernel<<<dim3(128), block, 0, stream>>>(hidden, gate_w, bias, counter,
                                                list, out, nrows);
}